// Round 13
// baseline (2943.520 us; speedup 1.0000x reference)
//
#include <hip/hip_runtime.h>

#define SEQ   512
#define BATCH 128
#define NFEAT 64
#define HID   256
#define HB    (BATCH * HID)   // 32768
#define NPAIR 8               // pairs of 8-batch sets; pair p owns sets {2p,2p+1}
#define GBLK  32              // blocks per pair: 2 layers x 16 col-tiles
#define SETW  2048            // words per (slot,set): 8 batches x 256 cols

// ---------------------------------------------------------------------------
// Persistent 2-layer LSTM, 256 blocks x 256 threads (1 block/CU).
// NEW this round: 2-way BATCH INTERLEAVING. The 128 batches split into 16
// independent sets of 8; pair p's 32 blocks (2 layers x 16 col-tiles) process
// set 2p (phase A) and set 2p+1 (phase B) alternately with the SAME register-
// resident weights. While phase A's h stores propagate through the fabric
// (W ~ 2.5-3us, proven invariant across r10/r12 protocols), the block runs
// phase B's staging+MFMA+gates, and vice versa: step time -> W + C_phase
// instead of W + C_full. Next-phase loads are issued right after S2 (before
// elementwise) so their latency hides under gate math.
// Each phase is a verbatim r12 exchange instance (absmax-verified): 4 slots
// (t&3), tag ((t>>2)%3)+1 packed into bit 0-1 of the lo-bf16, staged-progress
// flags for back-pressure (own-layer >= t-2, cross L0->L1 >= t-3), all spins
// bounded (bug -> wrong answer, never a timeout). Memory primitives: ONLY
// agent-scope relaxed atomics (r6/r9/r10/r12-verified). sc0-only blacklisted.
// MFMA: r6-verified bf16 hi/lo split; batch rows 8-15 of the B-fragment read
// pre-zeroed LDS and are discarded. c state: one register per phase.
// ---------------------------------------------------------------------------

typedef unsigned u32;
typedef unsigned long long u64;
typedef __attribute__((ext_vector_type(8))) short  short8;
typedef __attribute__((ext_vector_type(4))) float  f32x4;
typedef __attribute__((ext_vector_type(4))) unsigned short us4;

__device__ __forceinline__ unsigned short f2bf(float f) {  // RNE
    union { float f; unsigned u; } c; c.f = f;
    unsigned r = c.u + 0x7FFF + ((c.u >> 16) & 1);
    return (unsigned short)(r >> 16);
}
__device__ __forceinline__ float bf2f(unsigned short h) {
    union { float f; unsigned u; } c; c.u = ((unsigned)h) << 16;
    return c.f;
}

// agent-scope relaxed atomics -- the ONLY cross-block memory primitives.
__device__ __forceinline__ u64 ald64(const u64* p) {
    return __hip_atomic_load(p, __ATOMIC_RELAXED, __HIP_MEMORY_SCOPE_AGENT);
}
__device__ __forceinline__ u32 ald32(const u32* p) {
    return __hip_atomic_load(p, __ATOMIC_RELAXED, __HIP_MEMORY_SCOPE_AGENT);
}
__device__ __forceinline__ void ast32(u32* p, u32 v) {
    __hip_atomic_store(p, v, __ATOMIC_RELAXED, __HIP_MEMORY_SCOPE_AGENT);
}
__device__ __forceinline__ void agld16(const u32* p, u32 w[16]) {
    const u64* q = (const u64*)p;
    #pragma unroll
    for (int i = 0; i < 8; ++i) {
        const u64 v = ald64(q + i);
        w[2 * i] = (u32)v; w[2 * i + 1] = (u32)(v >> 32);
    }
}
// first check uses pre-issued w; reload only on tag mismatch
__device__ __forceinline__ void spin16(const u32* p, u32 w[16], u32 tag) {
    int guard = 0;
    for (;;) {
        bool ok = true;
        #pragma unroll
        for (int i = 0; i < 16; ++i) ok &= ((w[i] & 3u) == tag);
        if (ok || ++guard >= (1 << 14)) break;
        agld16(p, w);
    }
}

__global__ __launch_bounds__(256, 1) void lstm_persist(
    const float* __restrict__ X,      // [512][128][64]
    const float* __restrict__ w_ih0,  // [1024][64]
    const float* __restrict__ w_hh0,  // [1024][256]
    const float* __restrict__ b_ih0,
    const float* __restrict__ b_hh0,
    const float* __restrict__ w_ih1,  // [1024][256]
    const float* __restrict__ w_hh1,  // [1024][256]
    const float* __restrict__ b_ih1,
    const float* __restrict__ b_hh1,
    u32* __restrict__ h0p,            // [4 slots][16 sets][2048] tagged words
    u32* __restrict__ h1p,            // [4 slots][16 sets][2048] tagged words
    u32* __restrict__ flags)          // [2 phases][NPAIR][GBLK] stride 32 u32
{
    const int bid = blockIdx.x;
    const int tid = threadIdx.x;
    const int p     = bid >> 5;        // pair 0..7
    const int rk    = bid & 31;        // rank in pair-group
    const int layer = rk >> 4;         // 0 or 1
    const int ct    = rk & 15;         // col tile
    const int j0    = ct * 16;         // 16 h-cols
    const int setA  = 2 * p, setB = 2 * p + 1;

    const int wave = tid >> 6;
    const int l    = tid & 63;
    const int kq   = l >> 4;           // k-quarter within a k-tile
    const int ar   = l & 15;           // A row / B col (batch) within tile

    // staging roles: 8 batches x 32 chunk-slots
    const int b  = tid >> 5;           // batch row 0..7
    const int f0 = tid & 31;           // f0<16: own-h chunk; f0>=16: L1-x chunk
    const int pbloc = (tid & 127) >> 4;   // L0 x-writer batch row
    const int pf    = tid & 15;           // L0 x-writer float4 col

    __shared__ __align__(16) unsigned short hsh[16 * 512];
    __shared__ __align__(16) unsigned short hsl[16 * 512];
    __shared__ float red[4][4][16][20];   // [wave][gate][batch(ar)][col]
    __shared__ float bbuf[4][16];         // bias sums [gate][col]

    // zero planes once (rows 8..15 and k>=320 (L0) stay 0 forever)
    {
        const short8 z8 = {0, 0, 0, 0, 0, 0, 0, 0};
        for (int i = tid; i < 16 * 512 / 8; i += 256) {
            ((short8*)hsh)[i] = z8;
            ((short8*)hsl)[i] = z8;
        }
    }
    if (tid < 64) {
        const int gg = tid >> 4, cc = tid & 15;
        const float* bi_ = layer ? b_ih1 : b_ih0;
        const float* bh_ = layer ? b_hh1 : b_hh0;
        bbuf[gg][cc] = bi_[gg * 256 + j0 + cc] + bh_[gg * 256 + j0 + cc];
    }

    // ---- A-fragments: weight slice -> bf16 hi/lo, resident in VGPRs (r6) ----
    short8 Ahi[4][4], Alo[4][4];
    {
        const short8 z8 = {0, 0, 0, 0, 0, 0, 0, 0};
        #pragma unroll
        for (int gg = 0; gg < 4; ++gg) {
            const int row = gg * 256 + j0 + ar;
            #pragma unroll
            for (int kt = 0; kt < 4; ++kt) {
                const int k = (wave * 4 + kt) * 32 + kq * 8;
                const float* src = nullptr;
                if (layer) {
                    src = (k < 256) ? (w_ih1 + (size_t)row * 256 + k)
                                    : (w_hh1 + (size_t)row * 256 + (k - 256));
                } else {
                    if (k < 64)       src = w_ih0 + (size_t)row * 64 + k;
                    else if (k < 320) src = w_hh0 + (size_t)row * 256 + (k - 64);
                }
                short8 hi8 = z8, lo8 = z8;
                if (src) {
                    const float4 a = ((const float4*)src)[0];
                    const float4 bq = ((const float4*)src)[1];
                    const float wv[8] = {a.x, a.y, a.z, a.w, bq.x, bq.y, bq.z, bq.w};
                    #pragma unroll
                    for (int i = 0; i < 8; ++i) {
                        const unsigned short h = f2bf(wv[i]);
                        hi8[i] = (short)h;
                        lo8[i] = (short)f2bf(wv[i] - bf2f(h));
                    }
                }
                Ahi[gg][kt] = hi8;
                Alo[gg][kt] = lo8;
            }
        }
    }

    const int eb = tid >> 4, ecc = tid & 15;   // elementwise role (tid<128)
    float cregA = 0.f, cregB = 0.f;
    u32 wA[16], wB[16];

    u32* hown = layer ? h1p : h0p;
    const int hoff = layer ? 256 : 64;

    // issue next loads for (t, set) into w (role-matched addresses)
    auto issue = [&](int t, int set, u32* w) {
        if (t >= SEQ) return;
        if (t > 0 && f0 < 16)
            agld16(hown + ((size_t)(((t - 1) & 3) * 16 + set)) * SETW
                        + b * 256 + f0 * 16, w);
        else if (layer && f0 >= 16)
            agld16(h0p + ((size_t)((t & 3) * 16 + set)) * SETW
                       + b * 256 + (f0 - 16) * 16, w);
    };
    auto unpack_to = [&](const u32* w, int us, int sw) {
        short8 h0v, l0v, h1v, l1v;
        #pragma unroll
        for (int i = 0; i < 8; ++i) {
            h0v[i] = (short)(w[i] >> 16);     l0v[i] = (short)(w[i] & 0xFFFCu);
            h1v[i] = (short)(w[8 + i] >> 16); l1v[i] = (short)(w[8 + i] & 0xFFFCu);
        }
        *(short8*)&hsh[us ^ sw]       = h0v;
        *(short8*)&hsh[(us + 8) ^ sw] = h1v;
        *(short8*)&hsl[us ^ sw]       = l0v;
        *(short8*)&hsl[(us + 8) ^ sw] = l1v;
    };

    // phase front: bp-check, spin, unpack, S1, flag, xpf, MFMA, S2
    auto front = [&](int t, int set, u32* w, float4& xpf, bool xmine, int fb) {
        const int sp = (t - 1) & 3, st = t & 3;
        const u32 tgp = (t > 0) ? ((u32)((t - 1) >> 2) % 3u) + 1u : 0u;
        const u32 tgc = ((u32)(t >> 2) % 3u) + 1u;
        const int sw = b << 3;

        // back-pressure first check (non-blocking; verify below)
        const u32* faddr = nullptr; u32 fthr = 0, fval = 0;
        if (tid < 16) {
            if (tid != ct && t >= 3) {
                faddr = &flags[(size_t)(fb + layer * 16 + tid) * 32];
                fthr  = (u32)(t - 2);
            }
        } else if (tid < 32 && layer == 0 && t >= 4) {
            faddr = &flags[(size_t)(fb + 16 + (tid - 16)) * 32];
            fthr  = (u32)(t - 3);
        }
        if (faddr) fval = ald32(faddr);

        if (t > 0 && f0 < 16) {
            const u32* hp = hown + ((size_t)(sp * 16 + set)) * SETW + b * 256 + f0 * 16;
            spin16(hp, w, tgp);
            unpack_to(w, b * 512 + hoff + f0 * 16, sw);
        }
        if (layer) {
            if (f0 >= 16) {
                const u32* xp = h0p + ((size_t)(st * 16 + set)) * SETW
                                    + b * 256 + (f0 - 16) * 16;
                spin16(xp, w, tgc);
                unpack_to(w, b * 512 + (f0 - 16) * 16, sw);
            }
        } else if (xmine) {
            const float xv[4] = {xpf.x, xpf.y, xpf.z, xpf.w};
            us4 xh, xl;
            #pragma unroll
            for (int i = 0; i < 4; ++i) {
                const unsigned short hh = f2bf(xv[i]);
                xh[i] = hh;
                xl[i] = (unsigned short)(f2bf(xv[i] - bf2f(hh)) & 0xFFFF);
            }
            const int us = pbloc * 512 + pf * 4;
            const int sw2 = (pbloc & 7) << 3;
            *(us4*)&hsh[us ^ sw2] = xh;
            *(us4*)&hsl[us ^ sw2] = xl;
        }
        if (faddr) {   // back-pressure verify (stale thresholds; rarely spins)
            int guard = 0;
            while (fval < fthr && ++guard < (1 << 16)) fval = ald32(faddr);
        }
        __syncthreads();  // S1: staged planes visible

        if (tid == 0)
            ast32(&flags[(size_t)(fb + rk) * 32], (u32)(t + 1));
        if (!layer && xmine && t + 1 < SEQ)
            xpf = ((const float4*)(X + (size_t)(t + 1) * BATCH * NFEAT
                                     + (size_t)(set * 8 + pbloc) * NFEAT))[pf];

        {   // MFMA (r6-verified addressing)
            f32x4 acc[4];
            #pragma unroll
            for (int gg = 0; gg < 4; ++gg) acc[gg] = (f32x4){0.f, 0.f, 0.f, 0.f};
            #pragma unroll
            for (int kt = 0; kt < 4; ++kt) {
                const int KT = wave * 4 + kt;
                const int us = ar * 512 + KT * 32 + kq * 8;
                const int uswz = us ^ ((ar & 7) << 3);
                const short8 bh = *(const short8*)&hsh[uswz];
                const short8 bl = *(const short8*)&hsl[uswz];
                #pragma unroll
                for (int gg = 0; gg < 4; ++gg)
                    acc[gg] = __builtin_amdgcn_mfma_f32_16x16x32_bf16(
                        Ahi[gg][kt], bh, acc[gg], 0, 0, 0);
                #pragma unroll
                for (int gg = 0; gg < 4; ++gg)
                    acc[gg] = __builtin_amdgcn_mfma_f32_16x16x32_bf16(
                        Alo[gg][kt], bh, acc[gg], 0, 0, 0);
                #pragma unroll
                for (int gg = 0; gg < 4; ++gg)
                    acc[gg] = __builtin_amdgcn_mfma_f32_16x16x32_bf16(
                        Ahi[gg][kt], bl, acc[gg], 0, 0, 0);
            }
            #pragma unroll
            for (int gg = 0; gg < 4; ++gg)
                *(f32x4*)&red[wave][gg][ar][kq * 4] = acc[gg];
        }
        __syncthreads();  // S2: partials visible
    };

    // phase back: reduce + gates + tagged store (tid<128)
    auto back = [&](int t, int set, float& creg) {
        if (tid >= 128) return;
        const int st = t & 3;
        const u32 tgc = ((u32)(t >> 2) % 3u) + 1u;
        float pr[4];
        #pragma unroll
        for (int gg = 0; gg < 4; ++gg)
            pr[gg] = bbuf[gg][ecc] + red[0][gg][eb][ecc] + red[1][gg][eb][ecc]
                                   + red[2][gg][eb][ecc] + red[3][gg][eb][ecc];
        const float ig  = 1.0f / (1.0f + __expf(-pr[0]));
        const float fg  = 1.0f / (1.0f + __expf(-pr[1]));
        const float gg_ = tanhf(pr[2]);
        const float og  = 1.0f / (1.0f + __expf(-pr[3]));
        creg = fg * creg + ig * gg_;
        const float hv = og * tanhf(creg);
        const unsigned short hi = f2bf(hv);
        const unsigned short lo = f2bf(hv - bf2f(hi));
        ast32(&hown[((size_t)(st * 16 + set)) * SETW + eb * 256 + j0 + ecc],
              ((u32)hi << 16) | ((u32)lo & 0xFFFCu) | tgc);
    };

    // X prefetch initial (t=0)
    float4 xpfA = make_float4(0.f, 0.f, 0.f, 0.f);
    float4 xpfB = make_float4(0.f, 0.f, 0.f, 0.f);
    if (!layer) {
        if (tid < 128)
            xpfA = ((const float4*)(X + (size_t)(setA * 8 + pbloc) * NFEAT))[pf];
        else
            xpfB = ((const float4*)(X + (size_t)(setB * 8 + pbloc) * NFEAT))[pf];
    }
    const int fbA = 0 * NPAIR * GBLK + p * GBLK;
    const int fbB = 1 * NPAIR * GBLK + p * GBLK;

    __syncthreads();  // LDS zero + bias visible

    issue(0, setA, wA);   // prologue (L1-x only at t=0)
    issue(0, setB, wB);

    for (int t = 0; t < SEQ; ++t) {
        // ---- phase A ----
        front(t, setA, wA, xpfA, tid < 128, fbA);
        issue(t, setB, wB);            // B loads fly under A's gate math
        back(t, setA, cregA);
        // ---- phase B ----
        front(t, setB, wB, xpfB, tid >= 128, fbB);
        issue(t + 1, setA, wA);        // A(t+1) loads fly under B's gate math
        back(t, setB, cregB);
    }
}

// out[b] = dot(h1_last[b,:], fc_w) + fc_b ; h1[511] lives in slot 3
__global__ __launch_bounds__(64) void fc_kernel(
    const u32* __restrict__ h1p,
    const float* __restrict__ fc_w,
    const float* __restrict__ fc_b,
    float* __restrict__ out)
{
    const int bg   = blockIdx.x;       // global batch
    const int lane = threadIdx.x;
    const int set = bg >> 3, bb = bg & 7;
    const u32* row = h1p + ((size_t)(3 * 16 + set)) * SETW + bb * 256;
    float sum = 0.0f;
    #pragma unroll
    for (int k = lane; k < HID; k += 64) {
        const u32 w = row[k];
        const float h = bf2f((unsigned short)(w >> 16))
                      + bf2f((unsigned short)(w & 0xFFFCu));
        sum += h * fc_w[k];
    }
    #pragma unroll
    for (int off = 32; off > 0; off >>= 1)
        sum += __shfl_down(sum, off);
    if (lane == 0) out[bg] = sum + fc_b[0];
}

extern "C" void kernel_launch(void* const* d_in, const int* in_sizes, int n_in,
                              void* d_out, int out_size, void* d_ws, size_t ws_size,
                              hipStream_t stream)
{
    const float* X     = (const float*)d_in[0];
    const float* w_ih0 = (const float*)d_in[1];
    const float* w_hh0 = (const float*)d_in[2];
    const float* b_ih0 = (const float*)d_in[3];
    const float* b_hh0 = (const float*)d_in[4];
    const float* w_ih1 = (const float*)d_in[5];
    const float* w_hh1 = (const float*)d_in[6];
    const float* b_ih1 = (const float*)d_in[7];
    const float* b_hh1 = (const float*)d_in[8];
    const float* fc_w  = (const float*)d_in[9];
    const float* fc_b  = (const float*)d_in[10];

    u32* h0p   = (u32*)d_ws;             // [4][16][2048] tagged packed
    u32* h1p   = h0p + 4 * HB;           // [4][16][2048] tagged packed
    u32* flags = h1p + 4 * HB;           // 2*NPAIR*GBLK slots, stride 32 u32

    // zero h slots (tag=0) + flags every call; graph replays this memset so
    // stale tags/flags never leak across replays
    const size_t zbytes =
        (size_t)(8 * HB + 2 * NPAIR * GBLK * 32) * sizeof(u32);
    (void)hipMemsetAsync(d_ws, 0, zbytes, stream);

    lstm_persist<<<NPAIR * GBLK, 256, 0, stream>>>(X,
        w_ih0, w_hh0, b_ih0, b_hh0,
        w_ih1, w_hh1, b_ih1, b_hh1,
        h0p, h1p, flags);

    fc_kernel<<<BATCH, 64, 0, stream>>>(h1p, fc_w, fc_b, (float*)d_out);
}